// Round 6
// baseline (325.802 us; speedup 1.0000x reference)
//
#include <hip/hip_runtime.h>
#include <math.h>

#define BATCH   8
#define CCH     512
#define NHEADS  8
#define HD      64
#define NGROUPS 32
#define CPG     16
#define NSP     4096      // H*W
#define O1      1536      // 3*C

typedef __attribute__((ext_vector_type(8))) short          short8;
typedef __attribute__((ext_vector_type(8))) unsigned short ushort8;
typedef __attribute__((ext_vector_type(4))) unsigned short ushort4v;
typedef __attribute__((ext_vector_type(4))) float          float4v;

#define GLOAD_LDS16(g, s) __builtin_amdgcn_global_load_lds(                   \
    (const __attribute__((address_space(1))) void*)(g),                       \
    (__attribute__((address_space(3))) void*)(s), 16, 0, 0)

// ---------------------------------------------------------------------------
__device__ __forceinline__ float phi_act(float v) {   // elu(x)+1
    return v > 0.f ? v + 1.f : __expf(v);
}
__device__ __forceinline__ unsigned short f2bf(float f) {  // RNE fp32->bf16
    union { float f; unsigned int u; } c; c.f = f;
    unsigned int u = c.u;
    u += 0x7fffu + ((u >> 16) & 1u);
    return (unsigned short)(u >> 16);
}
__device__ __forceinline__ float bf2f(unsigned short s) {
    union { unsigned int u; float f; } c; c.u = ((unsigned int)s) << 16;
    return c.f;
}

// BK=64 LDS swizzle (rows of 128 B = 8 chunks of 16 B):
//  chunk c of row r lives at physical chunk c ^ (r & 7).
//  Staging: 1KB slab = 8 rows; lane ln writes physical (row=ln>>3, chunk=ln&7)
//    so it fetches GLOBAL chunk (ln&7) ^ (ln>>3).
//  Fragment read (quad,lm,kk): logical chunk kk*4+quad of row rb+lm (rb%16==0)
//    -> physical chunk (kk*4+quad) ^ (lm&7).  Worst 2 lanes/bank-group = free.

// ---------------------------------------------------------------------------
// Kernel 1: GroupNorm statistics -> per-(b,c) scale/shift
__global__ __launch_bounds__(256) void gn_stats(const float* __restrict__ x,
                                                const float* __restrict__ gamma,
                                                const float* __restrict__ beta,
                                                float* __restrict__ ss) {
    const int bg = blockIdx.x;
    const int t  = threadIdx.x;
    const float* base = x + (size_t)bg * (CPG * NSP);
    float s = 0.f, s2 = 0.f;
    #pragma unroll 4
    for (int i = 0; i < 64; ++i) {
        float4 v = *(const float4*)(base + (i * 256 + t) * 4);
        s  += v.x + v.y + v.z + v.w;
        s2 += v.x * v.x + v.y * v.y + v.z * v.z + v.w * v.w;
    }
    __shared__ float r1[256], r2[256];
    r1[t] = s; r2[t] = s2;
    __syncthreads();
    for (int off = 128; off > 0; off >>= 1) {
        if (t < off) { r1[t] += r1[t + off]; r2[t] += r2[t + off]; }
        __syncthreads();
    }
    if (t < CPG) {
        const float inv = 1.f / 65536.f;
        float mean = r1[0] * inv;
        float var  = r2[0] * inv - mean * mean;
        float rstd = rsqrtf(var + 1e-5f);
        int b = bg / NGROUPS, g = bg % NGROUPS;
        int c = g * CPG + t;
        float sc = gamma[c] * rstd;
        float sh = beta[c] - mean * sc;
        ss[(b * CCH + c) * 2]     = sc;
        ss[(b * CCH + c) * 2 + 1] = sh;
    }
}

// ---------------------------------------------------------------------------
// Kernel 2: weights fp32 -> bf16 (qkv_w 1536x512, proj_w 512x512)
__global__ __launch_bounds__(256) void conv_w(const float* __restrict__ qw,
                                              const float* __restrict__ pw,
                                              unsigned short* __restrict__ qwb,
                                              unsigned short* __restrict__ pwb) {
    int i = (blockIdx.x * 256 + threadIdx.x) * 4;
    if (i < O1 * CCH) {
        float4 v = *(const float4*)(qw + i);
        unsigned short o[4] = {f2bf(v.x), f2bf(v.y), f2bf(v.z), f2bf(v.w)};
        *(uint2*)(qwb + i) = *(uint2*)o;
    } else {
        int j = i - O1 * CCH;
        float4 v = *(const float4*)(pw + j);
        unsigned short o[4] = {f2bf(v.x), f2bf(v.y), f2bf(v.z), f2bf(v.w)};
        *(uint2*)(pwb + j) = *(uint2*)o;
    }
}

// ---------------------------------------------------------------------------
// Kernel 3: xnT[b][n][c] bf16 = GroupNorm(x)[b][c][n] transposed.
__global__ __launch_bounds__(256) void xnT_kernel(const float* __restrict__ x,
                                                  const float* __restrict__ ss,
                                                  unsigned short* __restrict__ xnT) {
    const int n0 = blockIdx.x * 64, c0 = blockIdx.y * 64, b = blockIdx.z;
    const int t = threadIdx.x;
    __shared__ float tile[64][65];
    const float* xb  = x + ((size_t)b * CCH + c0) * NSP + n0;
    const float* ssb = ss + b * CCH * 2;

    const int lr = t / 16, lc = (t % 16) * 4;
    #pragma unroll
    for (int j = 0; j < 4; ++j) {
        int cr = j * 16 + lr;
        float4 v = *(const float4*)(xb + (size_t)cr * NSP + lc);
        float sc = ssb[(c0 + cr) * 2], sh = ssb[(c0 + cr) * 2 + 1];
        tile[cr][lc + 0] = v.x * sc + sh;
        tile[cr][lc + 1] = v.y * sc + sh;
        tile[cr][lc + 2] = v.z * sc + sh;
        tile[cr][lc + 3] = v.w * sc + sh;
    }
    __syncthreads();
    #pragma unroll
    for (int j = 0; j < 2; ++j) {
        int wd = j * 256 + t;
        int n  = wd >> 3;
        int cb = (wd & 7) * 8;
        ushort8 o;
        #pragma unroll
        for (int i = 0; i < 8; ++i) o[i] = f2bf(tile[cb + i][n]);
        *(ushort8*)(xnT + ((size_t)b * NSP + n0 + n) * CCH + c0 + cb) = o;
    }
}

// ---------------------------------------------------------------------------
// Kernel 4: q GEMM (128o x 256n tile, BK=64, 4x8 frags/wave).
// mfma(w, x) -> rows=o. phi, 8B stores qT[b][n][c].
__global__ __launch_bounds__(256) void gemm_q(const unsigned short* __restrict__ A,
                                              const unsigned short* __restrict__ Bt,
                                              const float* __restrict__ bias,
                                              unsigned short* __restrict__ qT) {
    const int n0 = blockIdx.x * 256;
    const int o0 = blockIdx.y * 128;
    const int b  = blockIdx.z;
    const int t  = threadIdx.x;
    const int wv = t >> 6, ln = t & 63;
    const int quad = ln >> 4, lm = ln & 15;
    const int wo = (wv >> 1) * 64, wn = (wv & 1) * 128;

    __shared__ __align__(16) unsigned short As[128 * 64];   // 16 KB
    __shared__ __align__(16) unsigned short Bs[256 * 64];   // 32 KB

    float4v acc[4][8];
    #pragma unroll
    for (int i = 0; i < 4; ++i)
        #pragma unroll
        for (int j = 0; j < 8; ++j) acc[i][j] = {0.f, 0.f, 0.f, 0.f};

    const unsigned short* aBase = A + (size_t)o0 * CCH;
    const unsigned short* bBase = Bt + ((size_t)b * NSP + n0) * CCH;

    const int srow8 = ln >> 3;
    const int scs   = ((ln & 7) ^ srow8) * 8;
    const int lmp   = (lm & 7);

    for (int k0 = 0; k0 < CCH; k0 += 64) {
        __syncthreads();
        #pragma unroll
        for (int i = 0; i < 4; ++i) {               // A: slabs wv+4i (0..15)
            int s = wv + i * 4;
            GLOAD_LDS16(aBase + (size_t)(s * 8 + srow8) * CCH + k0 + scs,
                        As + s * 512);
        }
        #pragma unroll
        for (int i = 0; i < 8; ++i) {               // B: slabs wv+4i (0..31)
            int s = wv + i * 4;
            GLOAD_LDS16(bBase + (size_t)(s * 8 + srow8) * CCH + k0 + scs,
                        Bs + s * 512);
        }
        __syncthreads();
        #pragma unroll
        for (int kk = 0; kk < 2; ++kk) {
            const int sc8 = ((kk * 4 + quad) ^ lmp) * 8;
            short8 fw[4], fx[8];
            #pragma unroll
            for (int i = 0; i < 4; ++i)
                fw[i] = *(const short8*)(As + (wo + i * 16 + lm) * 64 + sc8);
            #pragma unroll
            for (int j = 0; j < 8; ++j)
                fx[j] = *(const short8*)(Bs + (wn + j * 16 + lm) * 64 + sc8);
            #pragma unroll
            for (int i = 0; i < 4; ++i)
                #pragma unroll
                for (int j = 0; j < 8; ++j)
                    acc[i][j] = __builtin_amdgcn_mfma_f32_16x16x32_bf16(
                        fw[i], fx[j], acc[i][j], 0, 0, 0);
        }
    }

    // rows=o (quad*4+r), cols=n (lm). phi, store 4 consecutive o.
    #pragma unroll
    for (int i = 0; i < 4; ++i) {
        int ob = o0 + wo + i * 16 + quad * 4;
        float4 b4 = *(const float4*)(bias + ob);
        float bs[4] = {b4.x, b4.y, b4.z, b4.w};
        #pragma unroll
        for (int j = 0; j < 8; ++j) {
            int n = n0 + wn + j * 16 + lm;
            ushort4v pk;
            #pragma unroll
            for (int r = 0; r < 4; ++r)
                pk[r] = f2bf(phi_act(acc[i][j][r] + bs[r]));
            *(ushort4v*)(qT + ((size_t)b * NSP + n) * CCH + ob) = pk;
        }
    }
}

// ---------------------------------------------------------------------------
// Kernel 5: k/v GEMM (128o x 256n tile, BK=64, 4x8 frags/wave).
// mfma(x, w) -> rows=n. 8B stores kb/vb[b][c][n]; phi for k.
// grid.y: 0..3 -> k, 4..7 -> v.
__global__ __launch_bounds__(256) void gemm_kv(const unsigned short* __restrict__ A,
                                               const unsigned short* __restrict__ Bt,
                                               const float* __restrict__ bias,
                                               unsigned short* __restrict__ kb,
                                               unsigned short* __restrict__ vb) {
    const int n0 = blockIdx.x * 256;
    const int o0 = 512 + blockIdx.y * 128;
    const int b  = blockIdx.z;
    const int t  = threadIdx.x;
    const int wv = t >> 6, ln = t & 63;
    const int quad = ln >> 4, lm = ln & 15;
    const int wo = (wv >> 1) * 64, wn = (wv & 1) * 128;

    __shared__ __align__(16) unsigned short As[128 * 64];
    __shared__ __align__(16) unsigned short Bs[256 * 64];

    float4v acc[4][8];
    #pragma unroll
    for (int i = 0; i < 4; ++i)
        #pragma unroll
        for (int j = 0; j < 8; ++j) acc[i][j] = {0.f, 0.f, 0.f, 0.f};

    const unsigned short* aBase = A + (size_t)o0 * CCH;
    const unsigned short* bBase = Bt + ((size_t)b * NSP + n0) * CCH;

    const int srow8 = ln >> 3;
    const int scs   = ((ln & 7) ^ srow8) * 8;
    const int lmp   = (lm & 7);

    for (int k0 = 0; k0 < CCH; k0 += 64) {
        __syncthreads();
        #pragma unroll
        for (int i = 0; i < 4; ++i) {
            int s = wv + i * 4;
            GLOAD_LDS16(aBase + (size_t)(s * 8 + srow8) * CCH + k0 + scs,
                        As + s * 512);
        }
        #pragma unroll
        for (int i = 0; i < 8; ++i) {
            int s = wv + i * 4;
            GLOAD_LDS16(bBase + (size_t)(s * 8 + srow8) * CCH + k0 + scs,
                        Bs + s * 512);
        }
        __syncthreads();
        #pragma unroll
        for (int kk = 0; kk < 2; ++kk) {
            const int sc8 = ((kk * 4 + quad) ^ lmp) * 8;
            short8 fw[4], fx[8];
            #pragma unroll
            for (int i = 0; i < 4; ++i)
                fw[i] = *(const short8*)(As + (wo + i * 16 + lm) * 64 + sc8);
            #pragma unroll
            for (int j = 0; j < 8; ++j)
                fx[j] = *(const short8*)(Bs + (wn + j * 16 + lm) * 64 + sc8);
            #pragma unroll
            for (int i = 0; i < 4; ++i)
                #pragma unroll
                for (int j = 0; j < 8; ++j)
                    acc[i][j] = __builtin_amdgcn_mfma_f32_16x16x32_bf16(
                        fx[j], fw[i], acc[i][j], 0, 0, 0);
        }
    }

    // rows=n (quad*4+r), cols=o (lm). store 4 consecutive n.
    const bool isk = (o0 < 1024);
    unsigned short* dst = isk ? kb : vb;
    const int coff = isk ? 512 : 1024;
    #pragma unroll
    for (int i = 0; i < 4; ++i) {
        int o = o0 + wo + i * 16 + lm;
        int c = o - coff;
        float bs = bias[o];
        #pragma unroll
        for (int j = 0; j < 8; ++j) {
            int n = n0 + wn + j * 16 + quad * 4;
            ushort4v pk;
            #pragma unroll
            for (int r = 0; r < 4; ++r) {
                float v = acc[i][j][r] + bs;
                if (isk) v = phi_act(v);
                pk[r] = f2bf(v);
            }
            *(ushort4v*)(dst + ((size_t)b * CCH + c) * NSP + n) = pk;
        }
    }
}

// ---------------------------------------------------------------------------
// Kernel 6: kv partials via MFMA + ksum via ones-MFMA.
// kv[d][e] = sum_n k[d][n]*v[e][n]; ks[d] = sum_n k[d][n].
__global__ __launch_bounds__(256) void kv_mfma(const unsigned short* __restrict__ kb,
                                               const unsigned short* __restrict__ vb,
                                               float* __restrict__ kvp,
                                               float* __restrict__ ksp) {
    const int chunk = blockIdx.x, bh = blockIdx.y;
    const int b = bh >> 3, h = bh & 7;
    const int t = threadIdx.x;
    const int wv = t >> 6, ln = t & 63;
    const int quad = ln >> 4, lm = ln & 15;
    const int wd = (wv >> 1) * 32, we = (wv & 1) * 32;

    __shared__ __align__(16) unsigned short kt[2 * 64 * 32];  // [kk][d][32n]
    __shared__ __align__(16) unsigned short vt[2 * 64 * 32];

    float4v acc[2][2];
    #pragma unroll
    for (int i = 0; i < 2; ++i)
        #pragma unroll
        for (int j = 0; j < 2; ++j) acc[i][j] = {0.f, 0.f, 0.f, 0.f};
    float4v ks0 = {0.f, 0.f, 0.f, 0.f}, ks1 = {0.f, 0.f, 0.f, 0.f};

    short8 ones;
    #pragma unroll
    for (int l = 0; l < 8; ++l) ones[l] = (short)0x3F80;   // bf16 1.0

    const unsigned short* kbase = kb + ((size_t)b * CCH + h * 64) * NSP + chunk * 1024;
    const unsigned short* vbase = vb + ((size_t)b * CCH + h * 64) * NSP + chunk * 1024;
    const int srow = ln >> 2;
    const int scs  = ((ln & 3) ^ ((ln >> 3) & 3)) * 8;
    const int sc8  = (quad ^ ((lm >> 1) & 3)) * 8;

    for (int it = 0; it < 16; ++it) {
        int noff = it * 64;
        __syncthreads();
        GLOAD_LDS16(kbase + (size_t)(wv * 16 + srow) * NSP + noff + scs,      kt + wv * 512);
        GLOAD_LDS16(kbase + (size_t)(wv * 16 + srow) * NSP + noff + 32 + scs, kt + 2048 + wv * 512);
        GLOAD_LDS16(vbase + (size_t)(wv * 16 + srow) * NSP + noff + scs,      vt + wv * 512);
        GLOAD_LDS16(vbase + (size_t)(wv * 16 + srow) * NSP + noff + 32 + scs, vt + 2048 + wv * 512);
        __syncthreads();
        #pragma unroll
        for (int kk = 0; kk < 2; ++kk) {
            short8 a0 = *(const short8*)(kt + kk * 2048 + (wd + lm) * 32 + sc8);
            short8 a1 = *(const short8*)(kt + kk * 2048 + (wd + 16 + lm) * 32 + sc8);
            short8 b0 = *(const short8*)(vt + kk * 2048 + (we + lm) * 32 + sc8);
            short8 b1 = *(const short8*)(vt + kk * 2048 + (we + 16 + lm) * 32 + sc8);
            acc[0][0] = __builtin_amdgcn_mfma_f32_16x16x32_bf16(a0, b0, acc[0][0], 0, 0, 0);
            acc[0][1] = __builtin_amdgcn_mfma_f32_16x16x32_bf16(a0, b1, acc[0][1], 0, 0, 0);
            acc[1][0] = __builtin_amdgcn_mfma_f32_16x16x32_bf16(a1, b0, acc[1][0], 0, 0, 0);
            acc[1][1] = __builtin_amdgcn_mfma_f32_16x16x32_bf16(a1, b1, acc[1][1], 0, 0, 0);
            ks0 = __builtin_amdgcn_mfma_f32_16x16x32_bf16(a0, ones, ks0, 0, 0, 0);
            ks1 = __builtin_amdgcn_mfma_f32_16x16x32_bf16(a1, ones, ks1, 0, 0, 0);
        }
    }
    // kv: rows=d (quad*4+r), cols=e (lm) -> store [e][d], 4 consecutive d.
    #pragma unroll
    for (int i = 0; i < 2; ++i)
        #pragma unroll
        for (int j = 0; j < 2; ++j) {
            int e = we + j * 16 + lm;
            int d = wd + i * 16 + quad * 4;
            float4 r = {acc[i][j][0], acc[i][j][1], acc[i][j][2], acc[i][j][3]};
            *(float4*)(kvp + ((size_t)(chunk * 64 + bh) * 64 + e) * 64 + d) = r;
        }
    // ksum: all cols identical; store from we==0 waves, lane lm==0.
    if ((wv & 1) == 0 && lm == 0) {
        float* kd = ksp + (size_t)(chunk * 64 + bh) * 64;
        float4 r0 = {ks0[0], ks0[1], ks0[2], ks0[3]};
        float4 r1 = {ks1[0], ks1[1], ks1[2], ks1[3]};
        *(float4*)(kd + wd + quad * 4)      = r0;
        *(float4*)(kd + wd + 16 + quad * 4) = r1;
    }
}

// ---------------------------------------------------------------------------
// Kernel 7: reduce 4 chunk partials -> kvTb[bh][e][d] bf16, ksf[bh][d] fp32.
__global__ __launch_bounds__(256) void kv_reduce(const float* __restrict__ kvp,
                                                 const float* __restrict__ ksp,
                                                 unsigned short* __restrict__ kvTb,
                                                 float* __restrict__ ksf) {
    const int NKV = 64 * 64 * 64;   // 262144
    int idx4 = (blockIdx.x * 256 + threadIdx.x) * 4;
    if (idx4 < NKV) {
        float4 s = {0.f, 0.f, 0.f, 0.f};
        #pragma unroll
        for (int p = 0; p < 4; ++p) {
            float4 v = *(const float4*)(kvp + (size_t)p * NKV + idx4);
            s.x += v.x; s.y += v.y; s.z += v.z; s.w += v.w;
        }
        ushort4v o = {f2bf(s.x), f2bf(s.y), f2bf(s.z), f2bf(s.w)};
        *(ushort4v*)(kvTb + idx4) = o;
    } else if (idx4 - NKV < 64 * 64) {
        int i2 = idx4 - NKV;
        float4 s = {0.f, 0.f, 0.f, 0.f};
        #pragma unroll
        for (int p = 0; p < 4; ++p) {
            float4 v = *(const float4*)(ksp + p * 4096 + i2);
            s.x += v.x; s.y += v.y; s.z += v.z; s.w += v.w;
        }
        *(float4*)(ksf + i2) = s;
    }
}

// ---------------------------------------------------------------------------
// Kernel 8: attn via MFMA. out[n][e] = (sum_d qT[n][d]*kvT[e][d]) / den[n].
__global__ __launch_bounds__(256) void attn_mfma(const unsigned short* __restrict__ qT,
                                                 const unsigned short* __restrict__ kvTb,
                                                 const float* __restrict__ ksf,
                                                 unsigned short* __restrict__ attnT) {
    const int n0 = blockIdx.x * 256;
    const int bh = blockIdx.y;
    const int b = bh >> 3, h = bh & 7;
    const int t = threadIdx.x;
    const int wv = t >> 6, ln = t & 63;
    const int quad = ln >> 4, lm = ln & 15;
    const int nb = n0 + wv * 64;

    __shared__ __align__(16) unsigned short kvs[64 * 72];
    __shared__ float kss[64];

    #pragma unroll
    for (int l = 0; l < 2; ++l) {
        int ch = l * 256 + t;            // 512 chunks of 8 ushorts
        int e = ch >> 3, c8 = ch & 7;
        *(ushort8*)(kvs + e * 72 + c8 * 8) =
            *(const ushort8*)(kvTb + (size_t)bh * 4096 + ch * 8);
    }
    if (t < 64) kss[t] = ksf[bh * 64 + t];
    __syncthreads();

    short8 bq[4][2];
    #pragma unroll
    for (int j = 0; j < 4; ++j)
        #pragma unroll
        for (int kk = 0; kk < 2; ++kk) {
            int n = nb + j * 16 + lm;
            bq[j][kk] = *(const short8*)(qT + ((size_t)b * NSP + n) * CCH +
                                         h * 64 + kk * 32 + quad * 8);
        }
    short8 ak[4][2];
    #pragma unroll
    for (int i = 0; i < 4; ++i)
        #pragma unroll
        for (int kk = 0; kk < 2; ++kk)
            ak[i][kk] = *(const short8*)(kvs + (i * 16 + lm) * 72 + kk * 32 + quad * 8);

    float4v acc[4][4];
    #pragma unroll
    for (int i = 0; i < 4; ++i)
        #pragma unroll
        for (int j = 0; j < 4; ++j) acc[i][j] = {0.f, 0.f, 0.f, 0.f};
    #pragma unroll
    for (int kk = 0; kk < 2; ++kk)
        #pragma unroll
        for (int i = 0; i < 4; ++i)
            #pragma unroll
            for (int j = 0; j < 4; ++j)
                acc[i][j] = __builtin_amdgcn_mfma_f32_16x16x32_bf16(
                    ak[i][kk], bq[j][kk], acc[i][j], 0, 0, 0);

    // denominators: den[n=nb+j*16+lm] = sum_d q[n][d]*ksum[d]
    float rden[4];
    #pragma unroll
    for (int j = 0; j < 4; ++j) {
        float dp = 0.f;
        #pragma unroll
        for (int kk = 0; kk < 2; ++kk)
            #pragma unroll
            for (int l = 0; l < 8; ++l)
                dp += bf2f((unsigned short)bq[j][kk][l]) * kss[kk * 32 + quad * 8 + l];
        dp += __shfl_xor(dp, 16);
        dp += __shfl_xor(dp, 32);
        rden[j] = 1.f / (dp + 1e-6f);
    }

    // rows=e (quad*4+r), cols=n (lm): 4 consecutive e -> 8B store to attnT[n][c]
    #pragma unroll
    for (int i = 0; i < 4; ++i) {
        int e = i * 16 + quad * 4;
        #pragma unroll
        for (int j = 0; j < 4; ++j) {
            int n = nb + j * 16 + lm;
            ushort4v pk;
            #pragma unroll
            for (int r = 0; r < 4; ++r)
                pk[r] = f2bf(acc[i][j][r] * rden[j]);
            *(ushort4v*)(attnT + ((size_t)b * NSP + n) * CCH + h * 64 + e) = pk;
        }
    }
}

// ---------------------------------------------------------------------------
// Kernel 9: proj GEMM (128x128, BK=64). mfma(attnT, w) -> rows=n.
// float4 bias+resid epilogue (memory-floor kernel, unchanged).
__global__ __launch_bounds__(256) void gemm_proj(const unsigned short* __restrict__ A,
                                                 const unsigned short* __restrict__ Bt,
                                                 const float* __restrict__ bias,
                                                 const float* __restrict__ resid,
                                                 float* __restrict__ outF) {
    const int n0 = blockIdx.x * 128;
    const int o0 = blockIdx.y * 128;
    const int b  = blockIdx.z;
    const int t  = threadIdx.x;
    const int wv = t >> 6, ln = t & 63;
    const int quad = ln >> 4, lm = ln & 15;
    const int wo = (wv >> 1) * 64, wn = (wv & 1) * 64;

    __shared__ __align__(16) unsigned short As[128 * 64];
    __shared__ __align__(16) unsigned short Bs[128 * 64];

    float4v acc[4][4];
    #pragma unroll
    for (int i = 0; i < 4; ++i)
        #pragma unroll
        for (int j = 0; j < 4; ++j) acc[i][j] = {0.f, 0.f, 0.f, 0.f};

    const unsigned short* aBase = A + (size_t)o0 * CCH;
    const unsigned short* bBase = Bt + ((size_t)b * NSP + n0) * CCH;

    const int srow8 = ln >> 3;
    const int scs   = ((ln & 7) ^ srow8) * 8;
    const int lmp   = (lm & 7);

    for (int k0 = 0; k0 < CCH; k0 += 64) {
        __syncthreads();
        #pragma unroll
        for (int i = 0; i < 4; ++i) {
            int slab = wv + i * 4;
            GLOAD_LDS16(aBase + (size_t)(slab * 8 + srow8) * CCH + k0 + scs,
                        As + slab * 512);
            GLOAD_LDS16(bBase + (size_t)(slab * 8 + srow8) * CCH + k0 + scs,
                        Bs + slab * 512);
        }
        __syncthreads();
        #pragma unroll
        for (int kk = 0; kk < 2; ++kk) {
            const int sc8 = ((kk * 4 + quad) ^ lmp) * 8;
            short8 fw[4], fx[4];
            #pragma unroll
            for (int i = 0; i < 4; ++i)
                fw[i] = *(const short8*)(As + (wo + i * 16 + lm) * 64 + sc8);
            #pragma unroll
            for (int j = 0; j < 4; ++j)
                fx[j] = *(const short8*)(Bs + (wn + j * 16 + lm) * 64 + sc8);
            #pragma unroll
            for (int i = 0; i < 4; ++i)
                #pragma unroll
                for (int j = 0; j < 4; ++j)
                    acc[i][j] = __builtin_amdgcn_mfma_f32_16x16x32_bf16(
                        fx[j], fw[i], acc[i][j], 0, 0, 0);
        }
    }

    // rows=n (quad*4+r), cols=o (lm). float4 bias+resid epilogue.
    #pragma unroll
    for (int i = 0; i < 4; ++i) {
        int o = o0 + wo + i * 16 + lm;
        float bs = bias[o];
        #pragma unroll
        for (int j = 0; j < 4; ++j) {
            int n = n0 + wn + j * 16 + quad * 4;
            size_t off = ((size_t)b * CCH + o) * NSP + n;
            float4 rv = *(const float4*)(resid + off);
            float4 w = {acc[i][j][0] + bs + rv.x, acc[i][j][1] + bs + rv.y,
                        acc[i][j][2] + bs + rv.z, acc[i][j][3] + bs + rv.w};
            *(float4*)(outF + off) = w;
        }
    }
}

// ---------------------------------------------------------------------------
extern "C" void kernel_launch(void* const* d_in, const int* in_sizes, int n_in,
                              void* d_out, int out_size, void* d_ws, size_t ws_size,
                              hipStream_t stream) {
    const float* x      = (const float*)d_in[0];
    const float* gamma  = (const float*)d_in[1];
    const float* beta   = (const float*)d_in[2];
    const float* qkv_w  = (const float*)d_in[3];
    const float* qkv_b  = (const float*)d_in[4];
    const float* proj_w = (const float*)d_in[5];
    const float* proj_b = (const float*)d_in[6];
    float* out = (float*)d_out;

    // workspace layout (float units)
    float* ws   = (float*)d_ws;
    float* ss   = ws;                                   //    8192
    float* kvp  = ss + 8192;                            // 1048576
    float* ksp  = kvp + 4 * 64 * 64 * 64;               //   16384
    float* ksf  = ksp + 4 * 64 * 64;                    //    4096
    unsigned short* xnT   = (unsigned short*)(ksf + 64 * 64);
    unsigned short* qT    = xnT + (size_t)BATCH * NSP * CCH;
    unsigned short* kb    = qT  + (size_t)BATCH * NSP * CCH;
    unsigned short* vb    = kb  + (size_t)BATCH * NSP * CCH;
    unsigned short* attnT = vb  + (size_t)BATCH * NSP * CCH;
    unsigned short* kvTb  = attnT + (size_t)BATCH * NSP * CCH;
    unsigned short* wqb   = kvTb + (size_t)64 * 64 * 64;
    unsigned short* wpb   = wqb + (size_t)O1 * CCH;

    gn_stats<<<BATCH * NGROUPS, 256, 0, stream>>>(x, gamma, beta, ss);
    conv_w<<<(O1 * CCH + CCH * CCH) / 4 / 256, 256, 0, stream>>>(qkv_w, proj_w, wqb, wpb);
    xnT_kernel<<<dim3(NSP / 64, CCH / 64, BATCH), 256, 0, stream>>>(x, ss, xnT);

    gemm_q <<<dim3(NSP / 256, 4, BATCH), 256, 0, stream>>>(wqb, xnT, qkv_b, qT);
    gemm_kv<<<dim3(NSP / 256, 8, BATCH), 256, 0, stream>>>(wqb, xnT, qkv_b, kb, vb);

    kv_mfma<<<dim3(4, 64), 256, 0, stream>>>(kb, vb, kvp, ksp);
    kv_reduce<<<(64 * 64 * 64 + 64 * 64) / 4 / 256, 256, 0, stream>>>(kvp, ksp, kvTb, ksf);
    attn_mfma<<<dim3(NSP / 256, 64), 256, 0, stream>>>(qT, kvTb, ksf, attnT);

    gemm_proj<<<dim3(NSP / 128, CCH / 128, BATCH), 256, 0, stream>>>(
        wpb, attnT, proj_b, x, out);
}